// Round 1
// baseline (404.873 us; speedup 1.0000x reference)
//
#include <hip/hip_runtime.h>

#define DEVI __device__ __forceinline__

typedef __attribute__((ext_vector_type(8))) short short8;
typedef __attribute__((ext_vector_type(4))) float floatx4;

typedef const __attribute__((address_space(1))) void* gbl_ptr_t;
typedef __attribute__((address_space(3))) void* lds_ptr_t;

// ---------- bf16 helpers (manual, RNE) ----------
DEVI unsigned short f2bf(float f) {
  union { float f; unsigned int u; } v; v.f = f;
  unsigned int r = v.u + 0x7fffu + ((v.u >> 16) & 1u);
  return (unsigned short)(r >> 16);
}

// pack 2 fp32 -> 2 bf16 in one instr (RNE). lo = a, hi = b.
DEVI unsigned int cvt_pk_bf16(float a, float b) {
  unsigned int r;
  asm("v_cvt_pk_bf16_f32 %0, %1, %2" : "=v"(r) : "v"(a), "v"(b));
  return r;
}

// problem constants
constexpr int Bc = 4, Tc = 2048, Dc = 1024, Hc = 16, DHc = 64;
constexpr int Mrows = Bc * Tc;              // 8192
constexpr long PLANE = (long)Bc * Hc * Tc * DHc;  // 8388608 elems per q/k/v plane

// ---------- cast fp32 -> bf16 (vectorized) ----------
__global__ __launch_bounds__(256) void cast_f32_bf16(const float* __restrict__ in,
                                                     unsigned short* __restrict__ out, int n4) {
  int i = blockIdx.x * 256 + threadIdx.x;
  if (i < n4) {
    float4 v = ((const float4*)in)[i];
    ushort4 o;
    o.x = f2bf(v.x); o.y = f2bf(v.y); o.z = f2bf(v.z); o.w = f2bf(v.w);
    ((ushort4*)out)[i] = o;
  }
}

// ---------- transpose + cast: in fp32 [K,N] -> out bf16 [N,K] ----------
__global__ __launch_bounds__(256) void transpose_cast(const float* __restrict__ in,
                                                      unsigned short* __restrict__ out,
                                                      int K, int N) {
  __shared__ float tile[32][33];
  int bx = blockIdx.x * 32;  // N dim
  int by = blockIdx.y * 32;  // K dim
  int tx = threadIdx.x & 31, ty = threadIdx.x >> 5;  // ty 0..7
#pragma unroll
  for (int i = ty; i < 32; i += 8) tile[i][tx] = in[(long)(by + i) * N + bx + tx];
  __syncthreads();
#pragma unroll
  for (int i = ty; i < 32; i += 8) out[(long)(bx + i) * K + by + tx] = f2bf(tile[tx][i]);
}

// ---------- GEMM: C[M,N] = A[M,K](bf16) @ Bt[N,K](bf16)^T + bias ----------
// m97 structure: global_load_lds width=16 staging into UNPADDED LDS (dest must
// be base + lane*16 contiguous), 128x128 tile, BK=64, 4x4 acc/wave.
// MODE 0: scatter to qkv bf16. Q,K planes: [B*H][T][64]. V plane: TRANSPOSED
//         [B*H][64][T] so flash_attn can stage V^T with vector loads (no
//         per-tile scalar transpose). Same element count, different address.
// MODE 1: plain fp32 [M,N]
template <int MODE>
__global__ __launch_bounds__(256) void gemm_bt(const unsigned short* __restrict__ A,
                                               const unsigned short* __restrict__ Bt,
                                               const float* __restrict__ bias,
                                               void* __restrict__ Cout,
                                               int M, int N, int K) {
  constexpr int BK = 64;
  __shared__ __align__(16) short As[128 * 64];
  __shared__ __align__(16) short Bs[128 * 64];

  const int tid = threadIdx.x;
  const int wave = tid >> 6;
  const int lane = tid & 63;
  const int l16 = lane & 15;
  const int quad = lane >> 4;
  const int wm = (wave >> 1) * 64;
  const int wn = (wave & 1) * 64;
  const int rsub = lane >> 3;        // 0..7 row within 8-row chunk
  const int csub = (lane & 7) * 8;   // col (bf16 elems) within 64-col row

  const long row0 = (long)blockIdx.y * 128;
  const long col0 = (long)blockIdx.x * 128;

  floatx4 acc[4][4];
#pragma unroll
  for (int i = 0; i < 4; i++)
#pragma unroll
    for (int j = 0; j < 4; j++) acc[i][j] = (floatx4){0.f, 0.f, 0.f, 0.f};

  for (int k0 = 0; k0 < K; k0 += BK) {
#pragma unroll
    for (int c = 0; c < 4; c++) {
      int rb = (c * 4 + wave) * 8;   // 8-row chunk base, wave-uniform
      const unsigned short* sA = &A[(row0 + rb + rsub) * (long)K + k0 + csub];
      __builtin_amdgcn_global_load_lds((gbl_ptr_t)sA, (lds_ptr_t)&As[rb * 64], 16, 0, 0);
      const unsigned short* sB = &Bt[(col0 + rb + rsub) * (long)K + k0 + csub];
      __builtin_amdgcn_global_load_lds((gbl_ptr_t)sB, (lds_ptr_t)&Bs[rb * 64], 16, 0, 0);
    }
    __syncthreads();   // drains vmcnt -> tiles resident
#pragma unroll
    for (int kk = 0; kk < BK; kk += 32) {
      short8 af[4], bfr[4];
#pragma unroll
      for (int mt = 0; mt < 4; mt++)
        af[mt] = *(const short8*)&As[(wm + mt * 16 + l16) * 64 + kk + quad * 8];
#pragma unroll
      for (int nt = 0; nt < 4; nt++)
        bfr[nt] = *(const short8*)&Bs[(wn + nt * 16 + l16) * 64 + kk + quad * 8];
#pragma unroll
      for (int mt = 0; mt < 4; mt++)
#pragma unroll
        for (int nt = 0; nt < 4; nt++)
          acc[mt][nt] = __builtin_amdgcn_mfma_f32_16x16x32_bf16(af[mt], bfr[nt], acc[mt][nt], 0, 0, 0);
    }
    __syncthreads();
  }

#pragma unroll
  for (int mt = 0; mt < 4; mt++)
#pragma unroll
    for (int nt = 0; nt < 4; nt++)
#pragma unroll
      for (int r = 0; r < 4; r++) {
        long row = row0 + wm + mt * 16 + quad * 4 + r;
        long col = col0 + wn + nt * 16 + l16;
        float v = acc[mt][nt][r] + bias[col];
        if (MODE == 0) {
          int which = (int)(col >> 10);
          int hc = (int)col & 1023;
          int h = hc >> 6, d = hc & 63;
          int b = (int)(row >> 11), t = (int)row & 2047;
          long addr;
          if (which == 2) {
            // V^T: [bh][d][T]
            addr = 2 * PLANE + (long)((b * Hc + h) * DHc + d) * Tc + t;
          } else {
            addr = (long)which * PLANE + (((long)(b * Hc + h) * Tc + t) << 6) + d;
          }
          ((unsigned short*)Cout)[addr] = f2bf(v);
        } else {
          ((float*)Cout)[row * N + col] = v;
        }
      }
}

// ---------- flash attention v4 ----------
// qkv bf16: Q,K [B*H][T][64]; V TRANSPOSED [B*H][64][T]. out bf16 [B][T][H][64].
// Changes vs v3 (both attack VALUBusy=47% / MfmaUtil=12%):
//  1. V arrives pre-transposed from GEMM1 -> V staged exactly like K
//     (2x uint4 reg prefetch + 2x b128 LDS commit). Kills the 16 scalar
//     ds_write_b16 + extracts per lane per tile.
//  2. Swapped QK^T: mfma(K, Q) = S^T. C-layout then puts 4 CONSECUTIVE KEYS
//     of one q-row (col=l16) in each lane -> P packed with v_cvt_pk_bf16_f32
//     and stored as 4x ds_write_b64 (was 16x ds_write_b16 + 16 manual f2bf).
//     K/Q fragment LDS reads are unchanged (operand layouts are symmetric).
//     Row-sum partial becomes a scalar (all 16 lane values share q-row l16);
//     reduce = 2 shfl_xor across quads + 4 broadcasts in epilogue.
// Fixed-max softmax: p = exp2(s*cexp) directly; masked -> 0.
__global__ __launch_bounds__(256) void flash_attn(const unsigned short* __restrict__ qkv,
                                                  unsigned short* __restrict__ attn_out) {
  constexpr int PD = 72;
  __shared__ __align__(16) short Ks[64 * PD];
  __shared__ __align__(16) short Vts[64 * PD];    // [d][key]
  __shared__ __align__(16) short Ps[4 * 16 * PD]; // per-wave: [local qrow][key]

  const int tid = threadIdx.x;
  const int wave = tid >> 6;
  const int lane = tid & 63;
  const int l16 = lane & 15;
  const int quad = lane >> 4;

  const int bh = blockIdx.y;          // b*16 + h
  const long base = (long)bh * Tc * DHc;
  const unsigned short* Qg = qkv + base;
  const unsigned short* Kg = qkv + PLANE + base;
  const unsigned short* Vg = qkv + 2 * PLANE + base;  // [64 d][T]
  const int b = bh >> 4, h = bh & 15;

  constexpr float CEXP = 0.125f * 1.44269504f;  // 1/sqrt(64) folded into exp2
  short* Pw = &Ps[wave * 16 * PD];

  // staging coords (all 256 threads): rows c*32 + (tid>>3), cols (tid&7)*8
  const int kr = tid >> 3;            // 0..31
  const int kc = (tid & 7) * 8;

#pragma unroll 1
  for (int pass = 0; pass < 2; pass++) {
    const int qx = (pass == 0) ? (int)blockIdx.x : (31 - (int)blockIdx.x);
    const int q0 = qx * 64 + wave * 16;  // wave's first q row

    // Q fragment (B-operand now; same read pattern), loop-invariant
    short8 qf[2];
#pragma unroll
    for (int kk = 0; kk < 2; kk++)
      qf[kk] = *(const short8*)&Qg[(long)(q0 + l16) * 64 + kk * 32 + quad * 8];

    floatx4 oacc[4];
#pragma unroll
    for (int j = 0; j < 4; j++) oacc[j] = (floatx4){0.f, 0.f, 0.f, 0.f};
    float lpart = 0.f;   // partial row-sum for q-row (q0 + l16)

    const int ntiles = qx + 1;

    // prologue: prefetch tile 0 into regs (overlaps prev pass epilogue)
    uint4 Kreg[2], Vreg[2];
    Kreg[0] = *(const uint4*)&Kg[(long)kr * 64 + kc];
    Kreg[1] = *(const uint4*)&Kg[(long)(32 + kr) * 64 + kc];
    Vreg[0] = *(const uint4*)&Vg[(long)kr * Tc + kc];
    Vreg[1] = *(const uint4*)&Vg[(long)(32 + kr) * Tc + kc];

#pragma unroll 1
    for (int kt = 0; kt < ntiles; kt++) {
      __syncthreads();  // all waves done reading LDS from previous tile
      // commit staged regs to LDS (K and V^T, identical vector pattern)
      *(uint4*)&Ks[kr * PD + kc] = Kreg[0];
      *(uint4*)&Ks[(32 + kr) * PD + kc] = Kreg[1];
      *(uint4*)&Vts[kr * PD + kc] = Vreg[0];
      *(uint4*)&Vts[(32 + kr) * PD + kc] = Vreg[1];
      __syncthreads();  // staging visible
      // prefetch next tile (consumed after next barrier -> latency hidden)
      if (kt + 1 < ntiles) {
        long koff = (long)(kt + 1) * 64;
        Kreg[0] = *(const uint4*)&Kg[(koff + kr) * 64 + kc];
        Kreg[1] = *(const uint4*)&Kg[(koff + 32 + kr) * 64 + kc];
        Vreg[0] = *(const uint4*)&Vg[(long)kr * Tc + koff + kc];
        Vreg[1] = *(const uint4*)&Vg[(long)(32 + kr) * Tc + koff + kc];
      }

      // S^T = K @ Q^T : lane holds keys (nt*16 + quad*4 + r), q-row (q0+l16)
      floatx4 sacc[4];
#pragma unroll
      for (int j = 0; j < 4; j++) sacc[j] = (floatx4){0.f, 0.f, 0.f, 0.f};
#pragma unroll
      for (int kk = 0; kk < 2; kk++) {
        short8 kf[4];
#pragma unroll
        for (int nt = 0; nt < 4; nt++)
          kf[nt] = *(const short8*)&Ks[(nt * 16 + l16) * PD + kk * 32 + quad * 8];
#pragma unroll
        for (int nt = 0; nt < 4; nt++)
          sacc[nt] = __builtin_amdgcn_mfma_f32_16x16x32_bf16(kf[nt], qf[kk], sacc[nt], 0, 0, 0);
      }

      // causal mask: only the diagonal tile
      if (kt == qx) {
        const int qi = q0 + l16;
#pragma unroll
        for (int nt = 0; nt < 4; nt++) {
#pragma unroll
          for (int r = 0; r < 4; r++) {
            int ki = kt * 64 + nt * 16 + quad * 4 + r;
            if (ki > qi) sacc[nt][r] = -3.0e38f;
          }
        }
      }

      // p = exp2(s*cexp); pack 4 consecutive keys -> 1 b64 store per nt
#pragma unroll
      for (int nt = 0; nt < 4; nt++) {
        float p0 = exp2f(sacc[nt][0] * CEXP);
        float p1 = exp2f(sacc[nt][1] * CEXP);
        float p2 = exp2f(sacc[nt][2] * CEXP);
        float p3 = exp2f(sacc[nt][3] * CEXP);
        lpart += (p0 + p1) + (p2 + p3);
        uint2 w;
        w.x = cvt_pk_bf16(p0, p1);
        w.y = cvt_pk_bf16(p2, p3);
        *(uint2*)&Pw[l16 * PD + nt * 16 + quad * 4] = w;
      }

      // O += P @ V   (reads unchanged; Pw rows are local q-rows)
#pragma unroll
      for (int kk = 0; kk < 2; kk++) {
        short8 pf = *(const short8*)&Pw[l16 * PD + kk * 32 + quad * 8];
        short8 vf[4];
#pragma unroll
        for (int dt = 0; dt < 4; dt++)
          vf[dt] = *(const short8*)&Vts[(dt * 16 + l16) * PD + kk * 32 + quad * 8];
#pragma unroll
        for (int dt = 0; dt < 4; dt++)
          oacc[dt] = __builtin_amdgcn_mfma_f32_16x16x32_bf16(pf, vf[dt], oacc[dt], 0, 0, 0);
      }
    }

    // epilogue: reduce l across quads (lane -> full sum for q-row l16),
    // broadcast to the C-layout rows, normalize + store
    float l = lpart;
    l += __shfl_xor(l, 16);
    l += __shfl_xor(l, 32);
#pragma unroll
    for (int r = 0; r < 4; r++) {
      float lr = __shfl(l, quad * 4 + r);   // sum for q-row (q0 + quad*4 + r)
      float inv = 1.0f / lr;
      int t = q0 + quad * 4 + r;
#pragma unroll
      for (int dt = 0; dt < 4; dt++) {
        int d = dt * 16 + l16;
        attn_out[(((long)(b * Tc + t) * Hc + h) << 6) + d] = f2bf(oacc[dt][r] * inv);
      }
    }
  }
}

// ---------- launch ----------
extern "C" void kernel_launch(void* const* d_in, const int* in_sizes, int n_in,
                              void* d_out, int out_size, void* d_ws, size_t ws_size,
                              hipStream_t stream) {
  const float* x = (const float*)d_in[0];
  const float* Wqkv = (const float*)d_in[1];
  const float* bqkv = (const float*)d_in[2];
  const float* Wout = (const float*)d_in[3];
  const float* bout = (const float*)d_in[4];

  char* ws = (char*)d_ws;
  unsigned short* x_bf   = (unsigned short*)ws;                       // 16 MB
  unsigned short* wqkv_t = (unsigned short*)(ws + 16777216);          // 6 MB
  unsigned short* wout_t = (unsigned short*)(ws + 16777216 + 6291456);// 2 MB
  unsigned short* qkv    = (unsigned short*)(ws + 25165824);          // 48 MB
  unsigned short* attn   = x_bf;  // reuse: x_bf dead after GEMM1

  // 1. casts / transposes
  cast_f32_bf16<<<dim3(Mrows * Dc / 4 / 256), dim3(256), 0, stream>>>(x, x_bf, Mrows * Dc / 4);
  transpose_cast<<<dim3(3 * Dc / 32, Dc / 32), dim3(256), 0, stream>>>(Wqkv, wqkv_t, Dc, 3 * Dc);
  transpose_cast<<<dim3(Dc / 32, Dc / 32), dim3(256), 0, stream>>>(Wout, wout_t, Dc, Dc);

  // 2. QKV projection (V written transposed per-head)
  gemm_bt<0><<<dim3(3 * Dc / 128, Mrows / 128), dim3(256), 0, stream>>>(
      x_bf, wqkv_t, bqkv, qkv, Mrows, 3 * Dc, Dc);

  // 3. flash attention (paired q-tiles, uniform 33 key-tiles per block)
  flash_attn<<<dim3(16, Bc * Hc), dim3(256), 0, stream>>>(qkv, attn);

  // 4. output projection (fp32 out + bias)
  gemm_bt<1><<<dim3(Dc / 128, Mrows / 128), dim3(256), 0, stream>>>(
      attn, wout_t, bout, d_out, Mrows, Dc, Dc);
}

// Round 2
// 342.782 us; speedup vs baseline: 1.1811x; 1.1811x over previous
//
#include <hip/hip_runtime.h>

#define DEVI __device__ __forceinline__

typedef __attribute__((ext_vector_type(8))) short short8;
typedef __attribute__((ext_vector_type(4))) float floatx4;

typedef const __attribute__((address_space(1))) void* gbl_ptr_t;
typedef __attribute__((address_space(3))) void* lds_ptr_t;

// ---------- bf16 helpers (manual, RNE) ----------
DEVI unsigned short f2bf(float f) {
  union { float f; unsigned int u; } v; v.f = f;
  unsigned int r = v.u + 0x7fffu + ((v.u >> 16) & 1u);
  return (unsigned short)(r >> 16);
}

// pack 2 fp32 -> 2 bf16 in one instr (RNE). lo = a, hi = b.
DEVI unsigned int cvt_pk_bf16(float a, float b) {
  unsigned int r;
  asm("v_cvt_pk_bf16_f32 %0, %1, %2" : "=v"(r) : "v"(a), "v"(b));
  return r;
}

// problem constants
constexpr int Bc = 4, Tc = 2048, Dc = 1024, Hc = 16, DHc = 64;
constexpr int Mrows = Bc * Tc;              // 8192
constexpr long PLANE = (long)Bc * Hc * Tc * DHc;  // 8388608 elems per q/k/v plane

// ---------- cast fp32 -> bf16 (vectorized) ----------
__global__ __launch_bounds__(256) void cast_f32_bf16(const float* __restrict__ in,
                                                     unsigned short* __restrict__ out, int n4) {
  int i = blockIdx.x * 256 + threadIdx.x;
  if (i < n4) {
    float4 v = ((const float4*)in)[i];
    ushort4 o;
    o.x = f2bf(v.x); o.y = f2bf(v.y); o.z = f2bf(v.z); o.w = f2bf(v.w);
    ((ushort4*)out)[i] = o;
  }
}

// ---------- transpose + cast: in fp32 [K,N] -> out bf16 [N,K] ----------
__global__ __launch_bounds__(256) void transpose_cast(const float* __restrict__ in,
                                                      unsigned short* __restrict__ out,
                                                      int K, int N) {
  __shared__ float tile[32][33];
  int bx = blockIdx.x * 32;  // N dim
  int by = blockIdx.y * 32;  // K dim
  int tx = threadIdx.x & 31, ty = threadIdx.x >> 5;  // ty 0..7
#pragma unroll
  for (int i = ty; i < 32; i += 8) tile[i][tx] = in[(long)(by + i) * N + bx + tx];
  __syncthreads();
#pragma unroll
  for (int i = ty; i < 32; i += 8) out[(long)(bx + i) * K + by + tx] = f2bf(tile[tx][i]);
}

// ---------- GEMM: C[M,N] = A[M,K](bf16) @ Bt[N,K](bf16)^T + bias ----------
// m97 structure: global_load_lds width=16 staging into UNPADDED LDS (dest must
// be base + lane*16 contiguous), 128x128 tile, BK=64, 4x4 acc/wave.
// XCD-aware chunked block swizzle (T1): grids are multiples of 8 blocks, so the
// simple bijective form is valid; each XCD gets a contiguous row-panel chunk
// (A-panel reuse stays in its L2). K=1024 makes this GEMM partially BW-bound.
// MODE 0: scatter to qkv bf16 [3][B*H][T][64] (V row-major like Q/K — the
//         transposed-V global layout caused 16-way store scatter + ~356 MB
//         write amplification; reverted).
// MODE 1: plain fp32 [M,N]
template <int MODE>
__global__ __launch_bounds__(256) void gemm_bt(const unsigned short* __restrict__ A,
                                               const unsigned short* __restrict__ Bt,
                                               const float* __restrict__ bias,
                                               void* __restrict__ Cout,
                                               int M, int N, int K) {
  constexpr int BK = 64;
  __shared__ __align__(16) short As[128 * 64];
  __shared__ __align__(16) short Bs[128 * 64];

  const int tid = threadIdx.x;
  const int wave = tid >> 6;
  const int lane = tid & 63;
  const int l16 = lane & 15;
  const int quad = lane >> 4;
  const int wm = (wave >> 1) * 64;
  const int wn = (wave & 1) * 64;
  const int rsub = lane >> 3;        // 0..7 row within 8-row chunk
  const int csub = (lane & 7) * 8;   // col (bf16 elems) within 64-col row

  // XCD swizzle: orig linear id -> chunked id (bijective when nwg % 8 == 0)
  int nwg = gridDim.x * gridDim.y;
  int lin = blockIdx.y * gridDim.x + blockIdx.x;
  if ((nwg & 7) == 0) {
    int cpx = nwg >> 3;
    lin = (lin & 7) * cpx + (lin >> 3);
  }
  const int bx = lin % gridDim.x;
  const int by = lin / gridDim.x;

  const long row0 = (long)by * 128;
  const long col0 = (long)bx * 128;

  floatx4 acc[4][4];
#pragma unroll
  for (int i = 0; i < 4; i++)
#pragma unroll
    for (int j = 0; j < 4; j++) acc[i][j] = (floatx4){0.f, 0.f, 0.f, 0.f};

  for (int k0 = 0; k0 < K; k0 += BK) {
#pragma unroll
    for (int c = 0; c < 4; c++) {
      int rb = (c * 4 + wave) * 8;   // 8-row chunk base, wave-uniform
      const unsigned short* sA = &A[(row0 + rb + rsub) * (long)K + k0 + csub];
      __builtin_amdgcn_global_load_lds((gbl_ptr_t)sA, (lds_ptr_t)&As[rb * 64], 16, 0, 0);
      const unsigned short* sB = &Bt[(col0 + rb + rsub) * (long)K + k0 + csub];
      __builtin_amdgcn_global_load_lds((gbl_ptr_t)sB, (lds_ptr_t)&Bs[rb * 64], 16, 0, 0);
    }
    __syncthreads();   // drains vmcnt -> tiles resident
#pragma unroll
    for (int kk = 0; kk < BK; kk += 32) {
      short8 af[4], bfr[4];
#pragma unroll
      for (int mt = 0; mt < 4; mt++)
        af[mt] = *(const short8*)&As[(wm + mt * 16 + l16) * 64 + kk + quad * 8];
#pragma unroll
      for (int nt = 0; nt < 4; nt++)
        bfr[nt] = *(const short8*)&Bs[(wn + nt * 16 + l16) * 64 + kk + quad * 8];
#pragma unroll
      for (int mt = 0; mt < 4; mt++)
#pragma unroll
        for (int nt = 0; nt < 4; nt++)
          acc[mt][nt] = __builtin_amdgcn_mfma_f32_16x16x32_bf16(af[mt], bfr[nt], acc[mt][nt], 0, 0, 0);
    }
    __syncthreads();
  }

#pragma unroll
  for (int mt = 0; mt < 4; mt++)
#pragma unroll
    for (int nt = 0; nt < 4; nt++)
#pragma unroll
      for (int r = 0; r < 4; r++) {
        long row = row0 + wm + mt * 16 + quad * 4 + r;
        long col = col0 + wn + nt * 16 + l16;
        float v = acc[mt][nt][r] + bias[col];
        if (MODE == 0) {
          int which = (int)(col >> 10);
          int hc = (int)col & 1023;
          int h = hc >> 6, d = hc & 63;
          int b = (int)(row >> 11), t = (int)row & 2047;
          ((unsigned short*)Cout)[(long)which * PLANE +
                                  (((long)(b * Hc + h) * Tc + t) << 6) + d] = f2bf(v);
        } else {
          ((float*)Cout)[row * N + col] = v;
        }
      }
}

// ---------- flash attention v5 ----------
// qkv bf16 [3][B*H][T][64] (all row-major) -> attn bf16 [B][T][H][64].
// Verified pieces kept from v4 (passed, same absmax):
//  - Swapped QK^T: mfma(K, Q) = S^T. C-layout puts 4 CONSECUTIVE KEYS of one
//    q-row (col=l16) per lane -> P packed via v_cvt_pk_bf16_f32 and stored as
//    4x ds_write_b64 (vs 16x ds_write_b16 + 16 manual f2bf). Row-sum partial
//    is a scalar; reduce = 2 shfl_xor + 4 broadcasts in epilogue.
// Reverted from v4 (write-amplification regression):
//  - V stays row-major in global; per-tile LDS transpose via scalar b16 writes
//    (VALU cost ~16 ops/lane/tile, but no HBM blowup).
// Fixed-max softmax: p = exp2(s*cexp) directly; masked -> 0.
__global__ __launch_bounds__(256) void flash_attn(const unsigned short* __restrict__ qkv,
                                                  unsigned short* __restrict__ attn_out) {
  constexpr int PD = 72;
  __shared__ __align__(16) short Ks[64 * PD];
  __shared__ __align__(16) short Vts[64 * PD];    // transposed: [d][key]
  __shared__ __align__(16) short Ps[4 * 16 * PD]; // per-wave: [local qrow][key]

  const int tid = threadIdx.x;
  const int wave = tid >> 6;
  const int lane = tid & 63;
  const int l16 = lane & 15;
  const int quad = lane >> 4;

  const int bh = blockIdx.y;          // b*16 + h
  const long base = (long)bh * Tc * DHc;
  const unsigned short* Qg = qkv + base;
  const unsigned short* Kg = qkv + PLANE + base;
  const unsigned short* Vg = qkv + 2 * PLANE + base;
  const int b = bh >> 4, h = bh & 15;

  constexpr float CEXP = 0.125f * 1.44269504f;  // 1/sqrt(64) folded into exp2
  short* Pw = &Ps[wave * 16 * PD];

  // K staging coords: chunk c covers rows c*32 + (tid>>3), cols (tid&7)*8
  const int kr = tid >> 3;            // 0..31
  const int kc = (tid & 7) * 8;

#pragma unroll 1
  for (int pass = 0; pass < 2; pass++) {
    const int qx = (pass == 0) ? (int)blockIdx.x : (31 - (int)blockIdx.x);
    const int q0 = qx * 64 + wave * 16;  // wave's first q row

    // Q fragment (B-operand of swapped mfma; same read pattern), loop-invariant
    short8 qf[2];
#pragma unroll
    for (int kk = 0; kk < 2; kk++)
      qf[kk] = *(const short8*)&Qg[(long)(q0 + l16) * 64 + kk * 32 + quad * 8];

    floatx4 oacc[4];
#pragma unroll
    for (int j = 0; j < 4; j++) oacc[j] = (floatx4){0.f, 0.f, 0.f, 0.f};
    float lpart = 0.f;   // partial row-sum for q-row (q0 + l16)

    const int ntiles = qx + 1;

    // prologue: prefetch tile 0 into regs (overlaps prev pass epilogue)
    uint4 Kreg[2], Vreg[2];
    Kreg[0] = *(const uint4*)&Kg[(long)kr * 64 + kc];
    Kreg[1] = *(const uint4*)&Kg[(long)(32 + kr) * 64 + kc];
    Vreg[0] = *(const uint4*)&Vg[(long)lane * 64 + wave * 8];
    Vreg[1] = *(const uint4*)&Vg[(long)lane * 64 + (wave + 4) * 8];

#pragma unroll 1
    for (int kt = 0; kt < ntiles; kt++) {
      __syncthreads();  // all waves done reading LDS from previous tile
      // commit staged regs to LDS
      *(uint4*)&Ks[kr * PD + kc] = Kreg[0];
      *(uint4*)&Ks[(32 + kr) * PD + kc] = Kreg[1];
#pragma unroll
      for (int c = 0; c < 2; c++) {
        int dc = wave + 4 * c;
        unsigned short vb[8];
        *(uint4*)vb = Vreg[c];
#pragma unroll
        for (int j = 0; j < 8; j++) Vts[(dc * 8 + j) * PD + lane] = (short)vb[j];
      }
      __syncthreads();  // staging visible
      // prefetch next tile (consumed after next barrier -> latency hidden)
      if (kt + 1 < ntiles) {
        long koff = (long)(kt + 1) * 64;
        Kreg[0] = *(const uint4*)&Kg[(koff + kr) * 64 + kc];
        Kreg[1] = *(const uint4*)&Kg[(koff + 32 + kr) * 64 + kc];
        Vreg[0] = *(const uint4*)&Vg[(koff + lane) * 64 + wave * 8];
        Vreg[1] = *(const uint4*)&Vg[(koff + lane) * 64 + (wave + 4) * 8];
      }

      // S^T = K @ Q^T : lane holds keys (nt*16 + quad*4 + r), q-row (q0+l16)
      floatx4 sacc[4];
#pragma unroll
      for (int j = 0; j < 4; j++) sacc[j] = (floatx4){0.f, 0.f, 0.f, 0.f};
#pragma unroll
      for (int kk = 0; kk < 2; kk++) {
        short8 kf[4];
#pragma unroll
        for (int nt = 0; nt < 4; nt++)
          kf[nt] = *(const short8*)&Ks[(nt * 16 + l16) * PD + kk * 32 + quad * 8];
#pragma unroll
        for (int nt = 0; nt < 4; nt++)
          sacc[nt] = __builtin_amdgcn_mfma_f32_16x16x32_bf16(kf[nt], qf[kk], sacc[nt], 0, 0, 0);
      }

      // causal mask: only the diagonal tile
      if (kt == qx) {
        const int qi = q0 + l16;
#pragma unroll
        for (int nt = 0; nt < 4; nt++) {
#pragma unroll
          for (int r = 0; r < 4; r++) {
            int ki = kt * 64 + nt * 16 + quad * 4 + r;
            if (ki > qi) sacc[nt][r] = -3.0e38f;
          }
        }
      }

      // p = exp2(s*cexp); pack 4 consecutive keys -> 1 b64 store per nt
#pragma unroll
      for (int nt = 0; nt < 4; nt++) {
        float p0 = exp2f(sacc[nt][0] * CEXP);
        float p1 = exp2f(sacc[nt][1] * CEXP);
        float p2 = exp2f(sacc[nt][2] * CEXP);
        float p3 = exp2f(sacc[nt][3] * CEXP);
        lpart += (p0 + p1) + (p2 + p3);
        uint2 w;
        w.x = cvt_pk_bf16(p0, p1);
        w.y = cvt_pk_bf16(p2, p3);
        *(uint2*)&Pw[l16 * PD + nt * 16 + quad * 4] = w;
      }

      // O += P @ V   (Pw rows are local q-rows; Vts is [d][key])
#pragma unroll
      for (int kk = 0; kk < 2; kk++) {
        short8 pf = *(const short8*)&Pw[l16 * PD + kk * 32 + quad * 8];
        short8 vf[4];
#pragma unroll
        for (int dt = 0; dt < 4; dt++)
          vf[dt] = *(const short8*)&Vts[(dt * 16 + l16) * PD + kk * 32 + quad * 8];
#pragma unroll
        for (int dt = 0; dt < 4; dt++)
          oacc[dt] = __builtin_amdgcn_mfma_f32_16x16x32_bf16(pf, vf[dt], oacc[dt], 0, 0, 0);
      }
    }

    // epilogue: reduce l across quads (lane -> full sum for q-row l16),
    // broadcast to the C-layout rows, normalize + store
    float l = lpart;
    l += __shfl_xor(l, 16);
    l += __shfl_xor(l, 32);
#pragma unroll
    for (int r = 0; r < 4; r++) {
      float lr = __shfl(l, quad * 4 + r);   // sum for q-row (q0 + quad*4 + r)
      float inv = 1.0f / lr;
      int t = q0 + quad * 4 + r;
#pragma unroll
      for (int dt = 0; dt < 4; dt++) {
        int d = dt * 16 + l16;
        attn_out[(((long)(b * Tc + t) * Hc + h) << 6) + d] = f2bf(oacc[dt][r] * inv);
      }
    }
  }
}

// ---------- launch ----------
extern "C" void kernel_launch(void* const* d_in, const int* in_sizes, int n_in,
                              void* d_out, int out_size, void* d_ws, size_t ws_size,
                              hipStream_t stream) {
  const float* x = (const float*)d_in[0];
  const float* Wqkv = (const float*)d_in[1];
  const float* bqkv = (const float*)d_in[2];
  const float* Wout = (const float*)d_in[3];
  const float* bout = (const float*)d_in[4];

  char* ws = (char*)d_ws;
  unsigned short* x_bf   = (unsigned short*)ws;                       // 16 MB
  unsigned short* wqkv_t = (unsigned short*)(ws + 16777216);          // 6 MB
  unsigned short* wout_t = (unsigned short*)(ws + 16777216 + 6291456);// 2 MB
  unsigned short* qkv    = (unsigned short*)(ws + 25165824);          // 48 MB
  unsigned short* attn   = x_bf;  // reuse: x_bf dead after GEMM1

  // 1. casts / transposes
  cast_f32_bf16<<<dim3(Mrows * Dc / 4 / 256), dim3(256), 0, stream>>>(x, x_bf, Mrows * Dc / 4);
  transpose_cast<<<dim3(3 * Dc / 32, Dc / 32), dim3(256), 0, stream>>>(Wqkv, wqkv_t, Dc, 3 * Dc);
  transpose_cast<<<dim3(Dc / 32, Dc / 32), dim3(256), 0, stream>>>(Wout, wout_t, Dc, Dc);

  // 2. QKV projection
  gemm_bt<0><<<dim3(3 * Dc / 128, Mrows / 128), dim3(256), 0, stream>>>(
      x_bf, wqkv_t, bqkv, qkv, Mrows, 3 * Dc, Dc);

  // 3. flash attention (paired q-tiles, uniform 33 key-tiles per block)
  flash_attn<<<dim3(16, Bc * Hc), dim3(256), 0, stream>>>(qkv, attn);

  // 4. output projection (fp32 out + bias)
  gemm_bt<1><<<dim3(Dc / 128, Mrows / 128), dim3(256), 0, stream>>>(
      attn, wout_t, bout, d_out, Mrows, Dc, Dc);
}

// Round 4
// 338.788 us; speedup vs baseline: 1.1951x; 1.0118x over previous
//
#include <hip/hip_runtime.h>

#define DEVI __device__ __forceinline__

typedef __attribute__((ext_vector_type(8))) short short8;
typedef __attribute__((ext_vector_type(4))) float floatx4;

typedef const __attribute__((address_space(1))) void* gbl_ptr_t;
typedef __attribute__((address_space(3))) void* lds_ptr_t;

// ---------- bf16 helpers (manual, RNE) ----------
DEVI unsigned short f2bf(float f) {
  union { float f; unsigned int u; } v; v.f = f;
  unsigned int r = v.u + 0x7fffu + ((v.u >> 16) & 1u);
  return (unsigned short)(r >> 16);
}

// pack 2 fp32 -> 2 bf16 in one instr (RNE). lo = a, hi = b.
DEVI unsigned int cvt_pk_bf16(float a, float b) {
  unsigned int r;
  asm("v_cvt_pk_bf16_f32 %0, %1, %2" : "=v"(r) : "v"(a), "v"(b));
  return r;
}

// problem constants
constexpr int Bc = 4, Tc = 2048, Dc = 1024, Hc = 16, DHc = 64;
constexpr int Mrows = Bc * Tc;              // 8192
constexpr long PLANE = (long)Bc * Hc * Tc * DHc;  // 8388608 elems per q/k/v plane

// ---------- cast fp32 -> bf16 (vectorized) ----------
__global__ __launch_bounds__(256) void cast_f32_bf16(const float* __restrict__ in,
                                                     unsigned short* __restrict__ out, int n4) {
  int i = blockIdx.x * 256 + threadIdx.x;
  if (i < n4) {
    float4 v = ((const float4*)in)[i];
    ushort4 o;
    o.x = f2bf(v.x); o.y = f2bf(v.y); o.z = f2bf(v.z); o.w = f2bf(v.w);
    ((ushort4*)out)[i] = o;
  }
}

// ---------- transpose + cast: in fp32 [K,N] -> out bf16 [N,K] ----------
__global__ __launch_bounds__(256) void transpose_cast(const float* __restrict__ in,
                                                      unsigned short* __restrict__ out,
                                                      int K, int N) {
  __shared__ float tile[32][33];
  int bx = blockIdx.x * 32;  // N dim
  int by = blockIdx.y * 32;  // K dim
  int tx = threadIdx.x & 31, ty = threadIdx.x >> 5;  // ty 0..7
#pragma unroll
  for (int i = ty; i < 32; i += 8) tile[i][tx] = in[(long)(by + i) * N + bx + tx];
  __syncthreads();
#pragma unroll
  for (int i = ty; i < 32; i += 8) out[(long)(bx + i) * K + by + tx] = f2bf(tile[tx][i]);
}

// ---------- GEMM: C[M,N] = A[M,K](bf16) @ Bt[N,K](bf16)^T + bias ----------
// m97 structure: global_load_lds width=16 staging into UNPADDED LDS, 128x128
// tile, BK=64, 4x4 acc/wave. XCD-aware chunked block swizzle (bijective,
// grids % 8 == 0). MODE 0: scatter to qkv bf16 [3][B*H][T][64]; MODE 1: fp32.
template <int MODE>
__global__ __launch_bounds__(256) void gemm_bt(const unsigned short* __restrict__ A,
                                               const unsigned short* __restrict__ Bt,
                                               const float* __restrict__ bias,
                                               void* __restrict__ Cout,
                                               int M, int N, int K) {
  constexpr int BK = 64;
  __shared__ __align__(16) short As[128 * 64];
  __shared__ __align__(16) short Bs[128 * 64];

  const int tid = threadIdx.x;
  const int wave = tid >> 6;
  const int lane = tid & 63;
  const int l16 = lane & 15;
  const int quad = lane >> 4;
  const int wm = (wave >> 1) * 64;
  const int wn = (wave & 1) * 64;
  const int rsub = lane >> 3;        // 0..7 row within 8-row chunk
  const int csub = (lane & 7) * 8;   // col (bf16 elems) within 64-col row

  // XCD swizzle: orig linear id -> chunked id (bijective when nwg % 8 == 0)
  int nwg = gridDim.x * gridDim.y;
  int lin = blockIdx.y * gridDim.x + blockIdx.x;
  if ((nwg & 7) == 0) {
    int cpx = nwg >> 3;
    lin = (lin & 7) * cpx + (lin >> 3);
  }
  const int bx = lin % gridDim.x;
  const int by = lin / gridDim.x;

  const long row0 = (long)by * 128;
  const long col0 = (long)bx * 128;

  floatx4 acc[4][4];
#pragma unroll
  for (int i = 0; i < 4; i++)
#pragma unroll
    for (int j = 0; j < 4; j++) acc[i][j] = (floatx4){0.f, 0.f, 0.f, 0.f};

  for (int k0 = 0; k0 < K; k0 += BK) {
#pragma unroll
    for (int c = 0; c < 4; c++) {
      int rb = (c * 4 + wave) * 8;   // 8-row chunk base, wave-uniform
      const unsigned short* sA = &A[(row0 + rb + rsub) * (long)K + k0 + csub];
      __builtin_amdgcn_global_load_lds((gbl_ptr_t)sA, (lds_ptr_t)&As[rb * 64], 16, 0, 0);
      const unsigned short* sB = &Bt[(col0 + rb + rsub) * (long)K + k0 + csub];
      __builtin_amdgcn_global_load_lds((gbl_ptr_t)sB, (lds_ptr_t)&Bs[rb * 64], 16, 0, 0);
    }
    __syncthreads();   // drains vmcnt -> tiles resident
#pragma unroll
    for (int kk = 0; kk < BK; kk += 32) {
      short8 af[4], bfr[4];
#pragma unroll
      for (int mt = 0; mt < 4; mt++)
        af[mt] = *(const short8*)&As[(wm + mt * 16 + l16) * 64 + kk + quad * 8];
#pragma unroll
      for (int nt = 0; nt < 4; nt++)
        bfr[nt] = *(const short8*)&Bs[(wn + nt * 16 + l16) * 64 + kk + quad * 8];
#pragma unroll
      for (int mt = 0; mt < 4; mt++)
#pragma unroll
        for (int nt = 0; nt < 4; nt++)
          acc[mt][nt] = __builtin_amdgcn_mfma_f32_16x16x32_bf16(af[mt], bfr[nt], acc[mt][nt], 0, 0, 0);
    }
    __syncthreads();
  }

#pragma unroll
  for (int mt = 0; mt < 4; mt++)
#pragma unroll
    for (int nt = 0; nt < 4; nt++)
#pragma unroll
      for (int r = 0; r < 4; r++) {
        long row = row0 + wm + mt * 16 + quad * 4 + r;
        long col = col0 + wn + nt * 16 + l16;
        float v = acc[mt][nt][r] + bias[col];
        if (MODE == 0) {
          int which = (int)(col >> 10);
          int hc = (int)col & 1023;
          int h = hc >> 6, d = hc & 63;
          int b = (int)(row >> 11), t = (int)row & 2047;
          ((unsigned short*)Cout)[(long)which * PLANE +
                                  (((long)(b * Hc + h) * Tc + t) << 6) + d] = f2bf(v);
        } else {
          ((float*)Cout)[row * N + col] = v;
        }
      }
}

// ---------- flash attention v6 (resubmit: round-3 container failure was
// infrastructural — no compile/correctness signal; source unchanged) ----------
// qkv bf16 [3][B*H][T][64] -> attn bf16 [B][T][H][64].
// Diagnosis r2: latency-bound (MfmaUtil 9%, VALU 35%, HBM 27%, occ 23%).
// Fixes, all targeting resident-wave count + prefetch latency:
//  1. __launch_bounds__(256,8): VGPR 68 crossed the 64 boundary (waves/SIMD
//     halves at 64 per m69) -> force back to <=64. Plus V-prefetch moved
//     after P-store (next use is NEXT iter's commit) to cut 8 live regs
//     across QK^T/softmax.
//  2. Unpaired q-tiles: grid (32,64)=2048 blocks (was 1024 paired) so the
//     LDS limit (5 blocks/CU) is actually reachable and short blocks
//     backfill.
//  3. XCD-chunked swizzle: each XCD owns 8 contiguous heads (8 x 512KB K/V
//     = 4MB = its L2) -> prefetches hit L2 (~200cy) not HBM (~900cy).
//     qx reversed within chunk: longest blocks (qx=31) dispatch first (LPT).
// Kept verified: swapped QK^T (S^T), cvt_pk P-store (4x b64), scalar lpart,
// fixed-max softmax p = exp2(s*cexp), V row-major + scalar LDS transpose.
__global__ __launch_bounds__(256, 8) void flash_attn(const unsigned short* __restrict__ qkv,
                                                     unsigned short* __restrict__ attn_out) {
  constexpr int PD = 72;
  __shared__ __align__(16) short Ks[64 * PD];
  __shared__ __align__(16) short Vts[64 * PD];    // transposed: [d][key]
  __shared__ __align__(16) short Ps[4 * 16 * PD]; // per-wave: [local qrow][key]

  const int tid = threadIdx.x;
  const int wave = tid >> 6;
  const int lane = tid & 63;
  const int l16 = lane & 15;
  const int quad = lane >> 4;

  // swizzle: linear id -> (bh, qx); 2048 blocks, chunk = 256 per XCD
  const int lin = blockIdx.y * 32 + blockIdx.x;
  const int lin2 = (lin & 7) * 256 + (lin >> 3);   // bijective (2048 % 8 == 0)
  const int bh = lin2 >> 5;                        // XCD x owns heads [x*8, x*8+8)
  const int qx = 31 - (lin2 & 31);                 // longest-first within chunk

  const long base = (long)bh * Tc * DHc;
  const unsigned short* Qg = qkv + base;
  const unsigned short* Kg = qkv + PLANE + base;
  const unsigned short* Vg = qkv + 2 * PLANE + base;
  const int b = bh >> 4, h = bh & 15;

  constexpr float CEXP = 0.125f * 1.44269504f;  // 1/sqrt(64) folded into exp2
  short* Pw = &Ps[wave * 16 * PD];

  // K staging coords: chunk c covers rows c*32 + (tid>>3), cols (tid&7)*8
  const int kr = tid >> 3;            // 0..31
  const int kc = (tid & 7) * 8;

  const int q0 = qx * 64 + wave * 16;  // wave's first q row

  // Q fragment (B-operand of swapped mfma), loop-invariant
  short8 qf[2];
#pragma unroll
  for (int kk = 0; kk < 2; kk++)
    qf[kk] = *(const short8*)&Qg[(long)(q0 + l16) * 64 + kk * 32 + quad * 8];

  floatx4 oacc[4];
#pragma unroll
  for (int j = 0; j < 4; j++) oacc[j] = (floatx4){0.f, 0.f, 0.f, 0.f};
  float lpart = 0.f;   // partial row-sum for q-row (q0 + l16)

  const int ntiles = qx + 1;

  // prologue: prefetch tile 0 into regs
  uint4 Kreg[2], Vreg[2];
  Kreg[0] = *(const uint4*)&Kg[(long)kr * 64 + kc];
  Kreg[1] = *(const uint4*)&Kg[(long)(32 + kr) * 64 + kc];
  Vreg[0] = *(const uint4*)&Vg[(long)lane * 64 + wave * 8];
  Vreg[1] = *(const uint4*)&Vg[(long)lane * 64 + (wave + 4) * 8];

#pragma unroll 1
  for (int kt = 0; kt < ntiles; kt++) {
    __syncthreads();  // all waves done reading LDS from previous tile
    // commit staged regs to LDS
    *(uint4*)&Ks[kr * PD + kc] = Kreg[0];
    *(uint4*)&Ks[(32 + kr) * PD + kc] = Kreg[1];
#pragma unroll
    for (int c = 0; c < 2; c++) {
      int dc = wave + 4 * c;
      unsigned short vb[8];
      *(uint4*)vb = Vreg[c];
#pragma unroll
      for (int j = 0; j < 8; j++) Vts[(dc * 8 + j) * PD + lane] = (short)vb[j];
    }
    __syncthreads();  // staging visible
    // prefetch next K (consumed after next barrier); V prefetch deferred
    // until after P-store to cut 8 live VGPRs across QK^T/softmax.
    if (kt + 1 < ntiles) {
      long koff = (long)(kt + 1) * 64;
      Kreg[0] = *(const uint4*)&Kg[(koff + kr) * 64 + kc];
      Kreg[1] = *(const uint4*)&Kg[(koff + 32 + kr) * 64 + kc];
    }

    // S^T = K @ Q^T : lane holds keys (nt*16 + quad*4 + r), q-row (q0+l16)
    floatx4 sacc[4];
#pragma unroll
    for (int j = 0; j < 4; j++) sacc[j] = (floatx4){0.f, 0.f, 0.f, 0.f};
#pragma unroll
    for (int kk = 0; kk < 2; kk++) {
      short8 kf[4];
#pragma unroll
      for (int nt = 0; nt < 4; nt++)
        kf[nt] = *(const short8*)&Ks[(nt * 16 + l16) * PD + kk * 32 + quad * 8];
#pragma unroll
      for (int nt = 0; nt < 4; nt++)
        sacc[nt] = __builtin_amdgcn_mfma_f32_16x16x32_bf16(kf[nt], qf[kk], sacc[nt], 0, 0, 0);
    }

    // causal mask: only the diagonal tile
    if (kt == qx) {
      const int qi = q0 + l16;
#pragma unroll
      for (int nt = 0; nt < 4; nt++) {
#pragma unroll
        for (int r = 0; r < 4; r++) {
          int ki = kt * 64 + nt * 16 + quad * 4 + r;
          if (ki > qi) sacc[nt][r] = -3.0e38f;
        }
      }
    }

    // p = exp2(s*cexp); pack 4 consecutive keys -> 1 b64 store per nt
#pragma unroll
    for (int nt = 0; nt < 4; nt++) {
      float p0 = exp2f(sacc[nt][0] * CEXP);
      float p1 = exp2f(sacc[nt][1] * CEXP);
      float p2 = exp2f(sacc[nt][2] * CEXP);
      float p3 = exp2f(sacc[nt][3] * CEXP);
      lpart += (p0 + p1) + (p2 + p3);
      uint2 w;
      w.x = cvt_pk_bf16(p0, p1);
      w.y = cvt_pk_bf16(p2, p3);
      *(uint2*)&Pw[l16 * PD + nt * 16 + quad * 4] = w;
    }

    // prefetch next V (next use: commit after next barrier; PV hides latency)
    if (kt + 1 < ntiles) {
      long koff = (long)(kt + 1) * 64;
      Vreg[0] = *(const uint4*)&Vg[(koff + lane) * 64 + wave * 8];
      Vreg[1] = *(const uint4*)&Vg[(koff + lane) * 64 + (wave + 4) * 8];
    }

    // O += P @ V   (Pw rows are local q-rows; Vts is [d][key])
#pragma unroll
    for (int kk = 0; kk < 2; kk++) {
      short8 pf = *(const short8*)&Pw[l16 * PD + kk * 32 + quad * 8];
      short8 vf[4];
#pragma unroll
      for (int dt = 0; dt < 4; dt++)
        vf[dt] = *(const short8*)&Vts[(dt * 16 + l16) * PD + kk * 32 + quad * 8];
#pragma unroll
      for (int dt = 0; dt < 4; dt++)
        oacc[dt] = __builtin_amdgcn_mfma_f32_16x16x32_bf16(pf, vf[dt], oacc[dt], 0, 0, 0);
    }
  }

  // epilogue: reduce l across quads (lane -> full sum for q-row l16),
  // broadcast to the C-layout rows, normalize + store
  float l = lpart;
  l += __shfl_xor(l, 16);
  l += __shfl_xor(l, 32);
#pragma unroll
  for (int r = 0; r < 4; r++) {
    float lr = __shfl(l, quad * 4 + r);   // sum for q-row (q0 + quad*4 + r)
    float inv = 1.0f / lr;
    int t = q0 + quad * 4 + r;
#pragma unroll
    for (int dt = 0; dt < 4; dt++) {
      int d = dt * 16 + l16;
      attn_out[(((long)(b * Tc + t) * Hc + h) << 6) + d] = f2bf(oacc[dt][r] * inv);
    }
  }
}

// ---------- launch ----------
extern "C" void kernel_launch(void* const* d_in, const int* in_sizes, int n_in,
                              void* d_out, int out_size, void* d_ws, size_t ws_size,
                              hipStream_t stream) {
  const float* x = (const float*)d_in[0];
  const float* Wqkv = (const float*)d_in[1];
  const float* bqkv = (const float*)d_in[2];
  const float* Wout = (const float*)d_in[3];
  const float* bout = (const float*)d_in[4];

  char* ws = (char*)d_ws;
  unsigned short* x_bf   = (unsigned short*)ws;                       // 16 MB
  unsigned short* wqkv_t = (unsigned short*)(ws + 16777216);          // 6 MB
  unsigned short* wout_t = (unsigned short*)(ws + 16777216 + 6291456);// 2 MB
  unsigned short* qkv    = (unsigned short*)(ws + 25165824);          // 48 MB
  unsigned short* attn   = x_bf;  // reuse: x_bf dead after GEMM1

  // 1. casts / transposes
  cast_f32_bf16<<<dim3(Mrows * Dc / 4 / 256), dim3(256), 0, stream>>>(x, x_bf, Mrows * Dc / 4);
  transpose_cast<<<dim3(3 * Dc / 32, Dc / 32), dim3(256), 0, stream>>>(Wqkv, wqkv_t, Dc, 3 * Dc);
  transpose_cast<<<dim3(Dc / 32, Dc / 32), dim3(256), 0, stream>>>(Wout, wout_t, Dc, Dc);

  // 2. QKV projection
  gemm_bt<0><<<dim3(3 * Dc / 128, Mrows / 128), dim3(256), 0, stream>>>(
      x_bf, wqkv_t, bqkv, qkv, Mrows, 3 * Dc, Dc);

  // 3. flash attention (one q-tile per block, XCD-chunked swizzle in-kernel)
  flash_attn<<<dim3(32, Bc * Hc), dim3(256), 0, stream>>>(qkv, attn);

  // 4. output projection (fp32 out + bias)
  gemm_bt<1><<<dim3(Dc / 128, Mrows / 128), dim3(256), 0, stream>>>(
      attn, wout_t, bout, d_out, Mrows, Dc, Dc);
}

// Round 5
// 336.701 us; speedup vs baseline: 1.2025x; 1.0062x over previous
//
#include <hip/hip_runtime.h>

#define DEVI __device__ __forceinline__

typedef __attribute__((ext_vector_type(8))) short short8;
typedef __attribute__((ext_vector_type(4))) float floatx4;

typedef const __attribute__((address_space(1))) void* gbl_ptr_t;
typedef __attribute__((address_space(3))) void* lds_ptr_t;

// ---------- bf16 helpers (manual, RNE) ----------
DEVI unsigned short f2bf(float f) {
  union { float f; unsigned int u; } v; v.f = f;
  unsigned int r = v.u + 0x7fffu + ((v.u >> 16) & 1u);
  return (unsigned short)(r >> 16);
}

// pack 2 fp32 -> 2 bf16 in one instr (RNE). lo = a, hi = b.
DEVI unsigned int cvt_pk_bf16(float a, float b) {
  unsigned int r;
  asm("v_cvt_pk_bf16_f32 %0, %1, %2" : "=v"(r) : "v"(a), "v"(b));
  return r;
}

// XOR swizzle for [row][64]-short LDS tiles (G4 idiom: byte ^= (row&7)<<4).
// In short units: i ^ (((i>>6)&7)<<3). Keeps 8-short vectors intact (bits 0-2
// untouched), buffer bit (12) unaffected. Applied identically on write & read.
DEVI int swz(int i) { return i ^ ((i >> 3) & 56); }

// problem constants
constexpr int Bc = 4, Tc = 2048, Dc = 1024, Hc = 16, DHc = 64;
constexpr int Mrows = Bc * Tc;              // 8192
constexpr long PLANE = (long)Bc * Hc * Tc * DHc;  // 8388608 elems per q/k/v plane

// ---------- cast fp32 -> bf16 (vectorized) ----------
__global__ __launch_bounds__(256) void cast_f32_bf16(const float* __restrict__ in,
                                                     unsigned short* __restrict__ out, int n4) {
  int i = blockIdx.x * 256 + threadIdx.x;
  if (i < n4) {
    float4 v = ((const float4*)in)[i];
    ushort4 o;
    o.x = f2bf(v.x); o.y = f2bf(v.y); o.z = f2bf(v.z); o.w = f2bf(v.w);
    ((ushort4*)out)[i] = o;
  }
}

// ---------- transpose + cast: in fp32 [K,N] -> out bf16 [N,K] ----------
__global__ __launch_bounds__(256) void transpose_cast(const float* __restrict__ in,
                                                      unsigned short* __restrict__ out,
                                                      int K, int N) {
  __shared__ float tile[32][33];
  int bx = blockIdx.x * 32;  // N dim
  int by = blockIdx.y * 32;  // K dim
  int tx = threadIdx.x & 31, ty = threadIdx.x >> 5;  // ty 0..7
#pragma unroll
  for (int i = ty; i < 32; i += 8) tile[i][tx] = in[(long)(by + i) * N + bx + tx];
  __syncthreads();
#pragma unroll
  for (int i = ty; i < 32; i += 8) out[(long)(bx + i) * K + by + tx] = f2bf(tile[tx][i]);
}

// ---------- GEMM: C[M,N] = A[M,K](bf16) @ Bt[N,K](bf16)^T + bias ----------
// m97 structure: global_load_lds width=16 staging into UNPADDED LDS, 128x128
// tile, BK=64, 4x4 acc/wave. XCD-aware chunked block swizzle (bijective,
// grids % 8 == 0). MODE 0: scatter to qkv bf16 [3][B*H][T][64]; MODE 1: fp32.
template <int MODE>
__global__ __launch_bounds__(256) void gemm_bt(const unsigned short* __restrict__ A,
                                               const unsigned short* __restrict__ Bt,
                                               const float* __restrict__ bias,
                                               void* __restrict__ Cout,
                                               int M, int N, int K) {
  constexpr int BK = 64;
  __shared__ __align__(16) short As[128 * 64];
  __shared__ __align__(16) short Bs[128 * 64];

  const int tid = threadIdx.x;
  const int wave = tid >> 6;
  const int lane = tid & 63;
  const int l16 = lane & 15;
  const int quad = lane >> 4;
  const int wm = (wave >> 1) * 64;
  const int wn = (wave & 1) * 64;
  const int rsub = lane >> 3;        // 0..7 row within 8-row chunk
  const int csub = (lane & 7) * 8;   // col (bf16 elems) within 64-col row

  // XCD swizzle: orig linear id -> chunked id (bijective when nwg % 8 == 0)
  int nwg = gridDim.x * gridDim.y;
  int lin = blockIdx.y * gridDim.x + blockIdx.x;
  if ((nwg & 7) == 0) {
    int cpx = nwg >> 3;
    lin = (lin & 7) * cpx + (lin >> 3);
  }
  const int bx = lin % gridDim.x;
  const int by = lin / gridDim.x;

  const long row0 = (long)by * 128;
  const long col0 = (long)bx * 128;

  floatx4 acc[4][4];
#pragma unroll
  for (int i = 0; i < 4; i++)
#pragma unroll
    for (int j = 0; j < 4; j++) acc[i][j] = (floatx4){0.f, 0.f, 0.f, 0.f};

  for (int k0 = 0; k0 < K; k0 += BK) {
#pragma unroll
    for (int c = 0; c < 4; c++) {
      int rb = (c * 4 + wave) * 8;   // 8-row chunk base, wave-uniform
      const unsigned short* sA = &A[(row0 + rb + rsub) * (long)K + k0 + csub];
      __builtin_amdgcn_global_load_lds((gbl_ptr_t)sA, (lds_ptr_t)&As[rb * 64], 16, 0, 0);
      const unsigned short* sB = &Bt[(col0 + rb + rsub) * (long)K + k0 + csub];
      __builtin_amdgcn_global_load_lds((gbl_ptr_t)sB, (lds_ptr_t)&Bs[rb * 64], 16, 0, 0);
    }
    __syncthreads();   // drains vmcnt -> tiles resident
#pragma unroll
    for (int kk = 0; kk < BK; kk += 32) {
      short8 af[4], bfr[4];
#pragma unroll
      for (int mt = 0; mt < 4; mt++)
        af[mt] = *(const short8*)&As[(wm + mt * 16 + l16) * 64 + kk + quad * 8];
#pragma unroll
      for (int nt = 0; nt < 4; nt++)
        bfr[nt] = *(const short8*)&Bs[(wn + nt * 16 + l16) * 64 + kk + quad * 8];
#pragma unroll
      for (int mt = 0; mt < 4; mt++)
#pragma unroll
        for (int nt = 0; nt < 4; nt++)
          acc[mt][nt] = __builtin_amdgcn_mfma_f32_16x16x32_bf16(af[mt], bfr[nt], acc[mt][nt], 0, 0, 0);
    }
    __syncthreads();
  }

#pragma unroll
  for (int mt = 0; mt < 4; mt++)
#pragma unroll
    for (int nt = 0; nt < 4; nt++)
#pragma unroll
      for (int r = 0; r < 4; r++) {
        long row = row0 + wm + mt * 16 + quad * 4 + r;
        long col = col0 + wn + nt * 16 + l16;
        float v = acc[mt][nt][r] + bias[col];
        if (MODE == 0) {
          int which = (int)(col >> 10);
          int hc = (int)col & 1023;
          int h = hc >> 6, d = hc & 63;
          int b = (int)(row >> 11), t = (int)row & 2047;
          ((unsigned short*)Cout)[(long)which * PLANE +
                                  (((long)(b * Hc + h) * Tc + t) << 6) + d] = f2bf(v);
        } else {
          ((float*)Cout)[row * N + col] = v;
        }
      }
}

// ---------- flash attention v7 ----------
// qkv bf16 [3][B*H][T][64] -> attn bf16 [B][T][H][64].
// Diagnosis r4: FETCH fixed (29MB), but dur stuck at 145us with MfmaUtil 10%,
// VALU 37%, HBM 5%, LDS-pipe ~30% — nothing saturated => bound by the 2-barrier
// serial phase structure per tile (m233 signature).
// v7 changes (structure only; math identical to verified v6):
//  1. Double-buffered K/V in LDS -> ONE barrier per tile. Commit of tile t+1
//     placed between QK and softmax of tile t (overlaps compute). End-of-tile
//     barrier guarantees both "buf[cur] reads done" and "buf[cur^1] commit
//     visible". Prefetch depth 2 (regs for t+2 issued after commit frees them).
//  2. No +8 pad; XOR swizzle (byte ^= (row&7)<<4) on Ks/Vts/Ps read+write.
//     Footprint exactly 40960 B -> 4 blocks/CU (padded dbuf would be 3).
// Kept: swapped QK^T (S^T), cvt_pk P-store, scalar lpart, fixed-max softmax,
// XCD-chunked grid swizzle, V row-major + scalar LDS transpose.
__global__ __launch_bounds__(256, 8) void flash_attn(const unsigned short* __restrict__ qkv,
                                                     unsigned short* __restrict__ attn_out) {
  __shared__ __align__(16) short Ks[2 * 64 * 64];   // [buf][key][d]
  __shared__ __align__(16) short Vts[2 * 64 * 64];  // [buf][d][key]
  __shared__ __align__(16) short Ps[4 * 16 * 64];   // per-wave [qrow][key]

  const int tid = threadIdx.x;
  const int wave = tid >> 6;
  const int lane = tid & 63;
  const int l16 = lane & 15;
  const int quad = lane >> 4;

  // swizzle: linear id -> (bh, qx); 2048 blocks, chunk = 256 per XCD
  const int lin = blockIdx.y * 32 + blockIdx.x;
  const int lin2 = (lin & 7) * 256 + (lin >> 3);   // bijective (2048 % 8 == 0)
  const int bh = lin2 >> 5;                        // XCD x owns heads [x*8, x*8+8)
  const int qx = 31 - (lin2 & 31);                 // long blocks early per head

  const long base = (long)bh * Tc * DHc;
  const unsigned short* Qg = qkv + base;
  const unsigned short* Kg = qkv + PLANE + base;
  const unsigned short* Vg = qkv + 2 * PLANE + base;
  const int b = bh >> 4, h = bh & 15;

  constexpr float CEXP = 0.125f * 1.44269504f;  // 1/sqrt(64) folded into exp2

  // K staging coords: rows kr, kr+32; cols (tid&7)*8
  const int kr = tid >> 3;            // 0..31
  const int kc = (tid & 7) * 8;

  const int q0 = qx * 64 + wave * 16;  // wave's first q row

  // Q fragment (B-operand of swapped mfma), loop-invariant
  short8 qf[2];
#pragma unroll
  for (int kk = 0; kk < 2; kk++)
    qf[kk] = *(const short8*)&Qg[(long)(q0 + l16) * 64 + kk * 32 + quad * 8];

  floatx4 oacc[4];
#pragma unroll
  for (int j = 0; j < 4; j++) oacc[j] = (floatx4){0.f, 0.f, 0.f, 0.f};
  float lpart = 0.f;   // partial row-sum for q-row (q0 + l16)

  const int ntiles = qx + 1;

  uint4 Kreg[2], Vreg[2];
  // prologue: load tile 0, commit to buf 0, load tile 1, one barrier
  Kreg[0] = *(const uint4*)&Kg[(long)kr * 64 + kc];
  Kreg[1] = *(const uint4*)&Kg[(long)(32 + kr) * 64 + kc];
  Vreg[0] = *(const uint4*)&Vg[(long)lane * 64 + wave * 8];
  Vreg[1] = *(const uint4*)&Vg[(long)lane * 64 + (wave + 4) * 8];
  {
    *(uint4*)&Ks[swz(kr * 64 + kc)] = Kreg[0];
    *(uint4*)&Ks[swz((32 + kr) * 64 + kc)] = Kreg[1];
#pragma unroll
    for (int c = 0; c < 2; c++) {
      int dc = wave + 4 * c;
      unsigned short vb[8];
      *(uint4*)vb = Vreg[c];
#pragma unroll
      for (int j = 0; j < 8; j++) Vts[swz((dc * 8 + j) * 64 + lane)] = (short)vb[j];
    }
  }
  if (ntiles > 1) {
    Kreg[0] = *(const uint4*)&Kg[(long)(64 + kr) * 64 + kc];
    Kreg[1] = *(const uint4*)&Kg[(long)(96 + kr) * 64 + kc];
    Vreg[0] = *(const uint4*)&Vg[(long)(64 + lane) * 64 + wave * 8];
    Vreg[1] = *(const uint4*)&Vg[(long)(64 + lane) * 64 + (wave + 4) * 8];
  }
  __syncthreads();

#pragma unroll 1
  for (int kt = 0; kt < ntiles; kt++) {
    const int cb = (kt & 1) << 12;   // current buffer base (shorts)
    const int nb = cb ^ 4096;        // next buffer

    // S^T = K @ Q^T : lane holds keys (nt*16 + quad*4 + r), q-row (q0+l16)
    floatx4 sacc[4];
#pragma unroll
    for (int j = 0; j < 4; j++) sacc[j] = (floatx4){0.f, 0.f, 0.f, 0.f};
#pragma unroll
    for (int kk = 0; kk < 2; kk++) {
      short8 kf[4];
#pragma unroll
      for (int nt = 0; nt < 4; nt++)
        kf[nt] = *(const short8*)&Ks[swz(cb + (nt * 16 + l16) * 64 + kk * 32 + quad * 8)];
#pragma unroll
      for (int nt = 0; nt < 4; nt++)
        sacc[nt] = __builtin_amdgcn_mfma_f32_16x16x32_bf16(kf[nt], qf[kk], sacc[nt], 0, 0, 0);
    }

    // commit tile kt+1 into the other buffer (overlaps QK/softmax compute;
    // safe: end-of-tile-(kt-1) barrier means nobody reads buf nb this tile)
    if (kt + 1 < ntiles) {
      *(uint4*)&Ks[swz(nb + kr * 64 + kc)] = Kreg[0];
      *(uint4*)&Ks[swz(nb + (32 + kr) * 64 + kc)] = Kreg[1];
#pragma unroll
      for (int c = 0; c < 2; c++) {
        int dc = wave + 4 * c;
        unsigned short vb[8];
        *(uint4*)vb = Vreg[c];
#pragma unroll
        for (int j = 0; j < 8; j++) Vts[swz(nb + (dc * 8 + j) * 64 + lane)] = (short)vb[j];
      }
    }
    // prefetch tile kt+2 (regs just freed by the commit)
    if (kt + 2 < ntiles) {
      long koff = (long)(kt + 2) * 64;
      Kreg[0] = *(const uint4*)&Kg[(koff + kr) * 64 + kc];
      Kreg[1] = *(const uint4*)&Kg[(koff + 32 + kr) * 64 + kc];
      Vreg[0] = *(const uint4*)&Vg[(koff + lane) * 64 + wave * 8];
      Vreg[1] = *(const uint4*)&Vg[(koff + lane) * 64 + (wave + 4) * 8];
    }

    // causal mask: only the diagonal tile
    if (kt == qx) {
      const int qi = q0 + l16;
#pragma unroll
      for (int nt = 0; nt < 4; nt++) {
#pragma unroll
        for (int r = 0; r < 4; r++) {
          int ki = kt * 64 + nt * 16 + quad * 4 + r;
          if (ki > qi) sacc[nt][r] = -3.0e38f;
        }
      }
    }

    // p = exp2(s*cexp); pack 4 consecutive keys -> 1 b64 store per nt
#pragma unroll
    for (int nt = 0; nt < 4; nt++) {
      float p0 = exp2f(sacc[nt][0] * CEXP);
      float p1 = exp2f(sacc[nt][1] * CEXP);
      float p2 = exp2f(sacc[nt][2] * CEXP);
      float p3 = exp2f(sacc[nt][3] * CEXP);
      lpart += (p0 + p1) + (p2 + p3);
      uint2 w;
      w.x = cvt_pk_bf16(p0, p1);
      w.y = cvt_pk_bf16(p2, p3);
      *(uint2*)&Ps[swz(wave * 1024 + l16 * 64 + nt * 16 + quad * 4)] = w;
    }

    // O += P @ V   (Ps rows are local q-rows; Vts is [d][key])
#pragma unroll
    for (int kk = 0; kk < 2; kk++) {
      short8 pf = *(const short8*)&Ps[swz(wave * 1024 + l16 * 64 + kk * 32 + quad * 8)];
      short8 vf[4];
#pragma unroll
      for (int dt = 0; dt < 4; dt++)
        vf[dt] = *(const short8*)&Vts[swz(cb + (dt * 16 + l16) * 64 + kk * 32 + quad * 8)];
#pragma unroll
      for (int dt = 0; dt < 4; dt++)
        oacc[dt] = __builtin_amdgcn_mfma_f32_16x16x32_bf16(pf, vf[dt], oacc[dt], 0, 0, 0);
    }

    // single barrier per tile: reads of buf cb done + commit into nb visible
    if (kt + 1 < ntiles) __syncthreads();
  }

  // epilogue: reduce l across quads (lane -> full sum for q-row l16),
  // broadcast to the C-layout rows, normalize + store
  float l = lpart;
  l += __shfl_xor(l, 16);
  l += __shfl_xor(l, 32);
#pragma unroll
  for (int r = 0; r < 4; r++) {
    float lr = __shfl(l, quad * 4 + r);   // sum for q-row (q0 + quad*4 + r)
    float inv = 1.0f / lr;
    int t = q0 + quad * 4 + r;
#pragma unroll
    for (int dt = 0; dt < 4; dt++) {
      int d = dt * 16 + l16;
      attn_out[(((long)(b * Tc + t) * Hc + h) << 6) + d] = f2bf(oacc[dt][r] * inv);
    }
  }
}

// ---------- launch ----------
extern "C" void kernel_launch(void* const* d_in, const int* in_sizes, int n_in,
                              void* d_out, int out_size, void* d_ws, size_t ws_size,
                              hipStream_t stream) {
  const float* x = (const float*)d_in[0];
  const float* Wqkv = (const float*)d_in[1];
  const float* bqkv = (const float*)d_in[2];
  const float* Wout = (const float*)d_in[3];
  const float* bout = (const float*)d_in[4];

  char* ws = (char*)d_ws;
  unsigned short* x_bf   = (unsigned short*)ws;                       // 16 MB
  unsigned short* wqkv_t = (unsigned short*)(ws + 16777216);          // 6 MB
  unsigned short* wout_t = (unsigned short*)(ws + 16777216 + 6291456);// 2 MB
  unsigned short* qkv    = (unsigned short*)(ws + 25165824);          // 48 MB
  unsigned short* attn   = x_bf;  // reuse: x_bf dead after GEMM1

  // 1. casts / transposes
  cast_f32_bf16<<<dim3(Mrows * Dc / 4 / 256), dim3(256), 0, stream>>>(x, x_bf, Mrows * Dc / 4);
  transpose_cast<<<dim3(3 * Dc / 32, Dc / 32), dim3(256), 0, stream>>>(Wqkv, wqkv_t, Dc, 3 * Dc);
  transpose_cast<<<dim3(Dc / 32, Dc / 32), dim3(256), 0, stream>>>(Wout, wout_t, Dc, Dc);

  // 2. QKV projection
  gemm_bt<0><<<dim3(3 * Dc / 128, Mrows / 128), dim3(256), 0, stream>>>(
      x_bf, wqkv_t, bqkv, qkv, Mrows, 3 * Dc, Dc);

  // 3. flash attention (one q-tile per block, XCD-chunked swizzle in-kernel)
  flash_attn<<<dim3(32, Bc * Hc), dim3(256), 0, stream>>>(qkv, attn);

  // 4. output projection (fp32 out + bias)
  gemm_bt<1><<<dim3(Dc / 128, Mrows / 128), dim3(256), 0, stream>>>(
      attn, wout_t, bout, d_out, Mrows, Dc, Dc);
}